// Round 1
// 1068.010 us; speedup vs baseline: 1.8168x; 1.8168x over previous
//
#include <hip/hip_runtime.h>
#include <hip/hip_bf16.h>

#define N_NODES 200000
#define N_EDGES 200000
#define IN_C 512
#define HID_C 512
#define OUT_C 256
#define K_HOPS 10

typedef __hip_bfloat16 bf16;
typedef __attribute__((ext_vector_type(8))) short short8;
typedef __attribute__((ext_vector_type(4))) float floatx4;

__device__ __forceinline__ void async_copy16(const void* g, void* l) {
  __builtin_amdgcn_global_load_lds(
      (const __attribute__((address_space(1))) void*)g,
      (__attribute__((address_space(3))) void*)l, 16, 0, 0);
}

__device__ __forceinline__ float bf2f(unsigned short u) {
  unsigned int x = ((unsigned int)u) << 16;
  return __builtin_bit_cast(float, x);
}
__device__ __forceinline__ unsigned short f2bf(float f) {
  return __builtin_bit_cast(unsigned short, __float2bfloat16(f));
}

// ---- f32 -> bf16 cast (contiguous), 4 elems/thread ----
__global__ void cast_kernel(const float* __restrict__ in, unsigned short* __restrict__ out,
                            int n) {
  int i = (blockIdx.x * 256 + threadIdx.x) * 4;
  if (i < n) {
    float4 v = *(const float4*)(in + i);
    ushort4 p;
    p.x = f2bf(v.x); p.y = f2bf(v.y); p.z = f2bf(v.z); p.w = f2bf(v.w);
    *(ushort4*)(out + i) = p;
  }
}

// ---- W [K,N] f32 row-major -> WT [N,K] bf16 row-major ----
__global__ void transpose_cast_kernel(const float* __restrict__ W, bf16* __restrict__ WT,
                                      int Kd, int Nd) {
  int idx = blockIdx.x * 256 + threadIdx.x;
  if (idx < Kd * Nd) {
    int k = idx / Nd, n = idx - k * Nd;
    WT[(size_t)n * Kd + k] = __float2bfloat16(W[idx]);
  }
}

__global__ void deg_kernel(const int* __restrict__ rowIdx, float* __restrict__ deg, int E) {
  int e = blockIdx.x * 256 + threadIdx.x;
  if (e < E) atomicAdd(&deg[rowIdx[e]], 1.0f);
}

__global__ void coef_kernel(const int* __restrict__ rowIdx, const int* __restrict__ colIdx,
                            const float* __restrict__ deg, float* __restrict__ coef, int E) {
  int e = blockIdx.x * 256 + threadIdx.x;
  if (e < E) {
    float dr = deg[rowIdx[e]];
    float dc = deg[colIdx[e]];
    float a = dr > 0.f ? rsqrtf(dr) : 0.f;
    float b = dc > 0.f ? rsqrtf(dc) : 0.f;
    coef[e] = a * b;
  }
}

// C = A * BT^T (+bias), A [M,K] bf16 row-major, BT [N,K] bf16 row-major, bias f32.
// EPI 0: relu -> bf16 Cb.
// EPI 1: bf16 Cb = relu(v) (gather operand for hops) AND f32 Cacc = gamma[0]*v (un-relu'd).
template <int EPI>
__global__ __launch_bounds__(256)
void gemm_bt_kernel(const bf16* __restrict__ A, const bf16* __restrict__ BT,
                    const float* __restrict__ bias, int M, int N, int K,
                    bf16* __restrict__ Cb, float* __restrict__ Cacc,
                    const float* __restrict__ gamma) {
  __shared__ bf16 As[128 * 32];
  __shared__ bf16 Bs[128 * 32];

  const int tid = threadIdx.x;
  const int lane = tid & 63;
  const int wave = tid >> 6;
  const int m0 = blockIdx.x * 128;
  const int n0 = blockIdx.y * 128;

  floatx4 zero = {0.f, 0.f, 0.f, 0.f};
  floatx4 acc[4][4];
#pragma unroll
  for (int i = 0; i < 4; ++i)
#pragma unroll
    for (int j = 0; j < 4; ++j) acc[i][j] = zero;

  const int wm = (wave & 1) * 64;   // wave's 64x64 sub-tile
  const int wn = (wave >> 1) * 64;
  const int lrow = lane & 15;
  const int kgrp = lane >> 4;       // 0..3 -> which 8-elem k-chunk

  int ar0 = m0 + (tid >> 2);
  int ar1 = ar0 + 64;
  ar0 = ar0 < M ? ar0 : M - 1;      // clamp OOB rows (dup load; store is guarded)
  ar1 = ar1 < M ? ar1 : M - 1;
  const int kc = (tid & 3) * 8;

  const bf16* Ag0 = A + (size_t)ar0 * K + kc;
  const bf16* Ag1 = A + (size_t)ar1 * K + kc;
  const bf16* Bg0 = BT + (size_t)(n0 + (tid >> 2)) * K + kc;
  const bf16* Bg1 = BT + (size_t)(n0 + 64 + (tid >> 2)) * K + kc;

  bf16* Al0 = &As[tid * 8];
  bf16* Al1 = &As[tid * 8 + 2048];
  bf16* Bl0 = &Bs[tid * 8];
  bf16* Bl1 = &Bs[tid * 8 + 2048];

  for (int k0 = 0; k0 < K; k0 += 32) {
    async_copy16(Ag0 + k0, Al0);
    async_copy16(Ag1 + k0, Al1);
    async_copy16(Bg0 + k0, Bl0);
    async_copy16(Bg1 + k0, Bl1);
    __syncthreads();  // compiler emits vmcnt(0) drain before barrier
    short8 a[4], b[4];
#pragma unroll
    for (int i = 0; i < 4; ++i) {
      a[i] = *(const short8*)&As[(wm + i * 16 + lrow) * 32 + kgrp * 8];
      b[i] = *(const short8*)&Bs[(wn + i * 16 + lrow) * 32 + kgrp * 8];
    }
#pragma unroll
    for (int i = 0; i < 4; ++i)
#pragma unroll
      for (int j = 0; j < 4; ++j)
        acc[i][j] = __builtin_amdgcn_mfma_f32_16x16x32_bf16(a[i], b[j], acc[i][j], 0, 0, 0);
    __syncthreads();
  }

  // C/D layout: col = lane&15, row = (lane>>4)*4 + r   [m89-verified]
  const int crow = (lane >> 4) * 4;
  const int ccol = lane & 15;
  float g0 = 0.f;
  if (EPI == 1) g0 = gamma[0];
  float bcol[4];
#pragma unroll
  for (int j = 0; j < 4; ++j) bcol[j] = bias[n0 + wn + j * 16 + ccol];

#pragma unroll
  for (int i = 0; i < 4; ++i) {
#pragma unroll
    for (int r = 0; r < 4; ++r) {
      const int gr = m0 + wm + i * 16 + crow + r;
      if (gr < M) {
#pragma unroll
        for (int j = 0; j < 4; ++j) {
          const int gc = n0 + wn + j * 16 + ccol;
          float v = acc[i][j][r] + bcol[j];
          if (EPI == 0) {
            Cb[(size_t)gr * N + gc] = __float2bfloat16(fmaxf(v, 0.f));
          } else {
            // gathers always consume relu(h) (relu(coef*y) == coef*relu(y), coef>=0)
            Cb[(size_t)gr * N + gc] = __float2bfloat16(fmaxf(v, 0.f));
            Cacc[(size_t)gr * N + gc] = g0 * v;  // gamma0 * h, un-relu'd, f32
          }
        }
      }
    }
  }
}

// All K_HOPS hops fused. Identity (coef >= 0):
//   x_k[e] = (prod_{j<k} coef[c_j]) * relu(h[c_k]),  c_0=e, c_{j+1}=col[c_j]
//   out[e] = gamma0*h[e] + sum_k gamma_k * x_k[e]
// One wave per edge: scalar (SGPR) chain walk, 64 lanes x 4 channels gather/accum.
// prod hits exact 0 when the chain crosses a deg-0 column node (~37% of edges at
// the first step) -> uniform early exit, all remaining terms are exactly 0.
__global__ void fused_hop_kernel(const unsigned short* __restrict__ rh,
                                 const float* __restrict__ oacc,
                                 float* __restrict__ outp,
                                 const int* __restrict__ colIdx,
                                 const float* __restrict__ coef,
                                 const float* __restrict__ gamma) {
  int gtid = blockIdx.x * 256 + threadIdx.x;
  int e = __builtin_amdgcn_readfirstlane(gtid >> 6);  // wave-uniform edge
  int c4 = (gtid & 63) * 4;

  // issue the coalesced oacc stream read first; it overlaps the scalar chain
  float4 acc = *(const float4*)(oacc + (size_t)e * 256 + c4);

  int c = e;
  float prod = 1.0f;
#pragma unroll 1
  for (int k = 1; k <= K_HOPS; ++k) {
    prod *= coef[c];                 // prod = P_k = prod_{j<k} coef[c_j]
    if (prod == 0.0f) break;         // exact: all remaining terms are 0
    c = __builtin_amdgcn_readfirstlane(colIdx[c]);  // c = c_k, keep scalar
    float w = gamma[k] * prod;
    ushort4 pv = *(const ushort4*)(rh + (size_t)c * 256 + c4);  // relu(h)[c_k]
    acc.x += w * bf2f(pv.x);
    acc.y += w * bf2f(pv.y);
    acc.z += w * bf2f(pv.z);
    acc.w += w * bf2f(pv.w);
  }
  *(float4*)(outp + (size_t)e * 256 + c4) = acc;
}

extern "C" void kernel_launch(void* const* d_in, const int* in_sizes, int n_in,
                              void* d_out, int out_size, void* d_ws, size_t ws_size,
                              hipStream_t stream) {
  const float* x = (const float*)d_in[0];     // [N, 512] f32
  const int* edge = (const int*)d_in[1];      // [2,E] int32: row=edge[0:E), col=edge[E:2E)
  const float* W1 = (const float*)d_in[2];    // [512, 512] f32
  const float* b1 = (const float*)d_in[3];    // [512] f32
  const float* W2 = (const float*)d_in[4];    // [512, 256] f32
  const float* b2 = (const float*)d_in[5];    // [256] f32
  const float* gamma = (const float*)d_in[6]; // [11] f32
  float* out = (float*)d_out;                 // [N, 256] f32

  // workspace layout (bytes):
  //  region A [0, 204.8MB): xb16 (bf16 cast of x) during GEMM1;
  //                         reused as rh = bf16 relu(h) afterwards.
  char* ws = (char*)d_ws;
  unsigned short* xb16 = (unsigned short*)ws;              // N*512*2 = 204,800,000
  unsigned short* rh = (unsigned short*)ws;                // N*256*2 = 102,400,000
  bf16* h1 = (bf16*)(ws + 204800000);                      // N*512*2 = 204,800,000
  float* oacc = (float*)(ws + 409600000);                  // N*256*4 = 204,800,000
  bf16* W1T = (bf16*)(ws + 614400000);                     // 512*512*2 = 524,288
  bf16* W2T = (bf16*)(ws + 614924288);                     // 256*512*2 = 262,144
  float* deg = (float*)(ws + 615186432);                   // N*4 = 800,000
  float* coef = (float*)(ws + 615986432);                  // E*4 = 800,000

  const int* rowIdx = edge;
  const int* colIdx = edge + N_EDGES;

  hipMemsetAsync(deg, 0, N_NODES * sizeof(float), stream);

  cast_kernel<<<dim3(N_NODES * IN_C / 4 / 256), 256, 0, stream>>>(x, xb16, N_NODES * IN_C);
  transpose_cast_kernel<<<dim3(IN_C * HID_C / 256), 256, 0, stream>>>(W1, W1T, IN_C, HID_C);
  transpose_cast_kernel<<<dim3(HID_C * OUT_C / 256), 256, 0, stream>>>(W2, W2T, HID_C, OUT_C);

  deg_kernel<<<dim3((N_EDGES + 255) / 256), 256, 0, stream>>>(rowIdx, deg, N_EDGES);
  coef_kernel<<<dim3((N_EDGES + 255) / 256), 256, 0, stream>>>(rowIdx, colIdx, deg, coef, N_EDGES);

  // h1 = relu(x @ W1 + b1) [N,512] bf16
  gemm_bt_kernel<0><<<dim3((N_NODES + 127) / 128, HID_C / 128), 256, 0, stream>>>(
      (const bf16*)xb16, W1T, b1, N_NODES, HID_C, IN_C, h1, nullptr, nullptr);
  // rh = relu(h1 @ W2 + b2) bf16; oacc = gamma[0]*(h1 @ W2 + b2) f32
  gemm_bt_kernel<1><<<dim3((N_NODES + 127) / 128, OUT_C / 128), 256, 0, stream>>>(
      h1, W2T, b2, N_NODES, OUT_C, HID_C, (bf16*)rh, oacc, gamma);

  // all 10 hops in one pass
  fused_hop_kernel<<<dim3(N_EDGES * 64 / 256), 256, 0, stream>>>(
      rh, oacc, out, colIdx, coef, gamma);
}

// Round 2
// 1051.546 us; speedup vs baseline: 1.8453x; 1.0157x over previous
//
#include <hip/hip_runtime.h>
#include <hip/hip_bf16.h>

#define N_NODES 200000
#define N_EDGES 200000
#define IN_C 512
#define HID_C 512
#define OUT_C 256
#define K_HOPS 10

typedef __hip_bfloat16 bf16;
typedef __attribute__((ext_vector_type(8))) short short8;
typedef __attribute__((ext_vector_type(4))) float floatx4;

__device__ __forceinline__ void async_copy16(const void* g, void* l) {
  __builtin_amdgcn_global_load_lds(
      (const __attribute__((address_space(1))) void*)g,
      (__attribute__((address_space(3))) void*)l, 16, 0, 0);
}

__device__ __forceinline__ float bf2f(unsigned short u) {
  unsigned int x = ((unsigned int)u) << 16;
  return __builtin_bit_cast(float, x);
}
__device__ __forceinline__ unsigned short f2bf(float f) {
  return __builtin_bit_cast(unsigned short, __float2bfloat16(f));
}

__device__ __forceinline__ short8 pack8(float4 lo, float4 hi) {
  short8 r;
  r[0] = (short)f2bf(lo.x); r[1] = (short)f2bf(lo.y);
  r[2] = (short)f2bf(lo.z); r[3] = (short)f2bf(lo.w);
  r[4] = (short)f2bf(hi.x); r[5] = (short)f2bf(hi.y);
  r[6] = (short)f2bf(hi.z); r[7] = (short)f2bf(hi.w);
  return r;
}

// ---- W [K,N] f32 row-major -> WT [N,K] bf16 row-major ----
__global__ void transpose_cast_kernel(const float* __restrict__ W, bf16* __restrict__ WT,
                                      int Kd, int Nd) {
  int idx = blockIdx.x * 256 + threadIdx.x;
  if (idx < Kd * Nd) {
    int k = idx / Nd, n = idx - k * Nd;
    WT[(size_t)n * Kd + k] = __float2bfloat16(W[idx]);
  }
}

__global__ void deg_kernel(const int* __restrict__ rowIdx, float* __restrict__ deg, int E) {
  int e = blockIdx.x * 256 + threadIdx.x;
  if (e < E) atomicAdd(&deg[rowIdx[e]], 1.0f);
}

__global__ void coef_kernel(const int* __restrict__ rowIdx, const int* __restrict__ colIdx,
                            const float* __restrict__ deg, float* __restrict__ coef, int E) {
  int e = blockIdx.x * 256 + threadIdx.x;
  if (e < E) {
    float dr = deg[rowIdx[e]];
    float dc = deg[colIdx[e]];
    float a = dr > 0.f ? rsqrtf(dr) : 0.f;
    float b = dc > 0.f ? rsqrtf(dc) : 0.f;
    coef[e] = a * b;
  }
}

// Fused MLP: rh = relu(relu(X@W1+b1)@W2+b2) bf16, oacc = gamma[0]*(relu(X@W1+b1)@W2+b2) f32.
// Block = 128 rows x full width. Stage-1: h1[128x512] in registers (8 waves x 64x128,
// acc1[4][8] = 128 VGPR/lane), X staged as raw f32 via global_load_lds, converted to bf16
// at fragment read (x read from HBM exactly once). Stage-2: h1 -> LDS bf16 (K-major chunk
// layout [k-chunk][row] -> conflict-free ds_read_b128), x W2T frags from global (L2-hot).
__global__ __launch_bounds__(512, 2)
void fused_mlp_kernel(const float* __restrict__ X, const bf16* __restrict__ W1T,
                      const float* __restrict__ b1, const bf16* __restrict__ W2T,
                      const float* __restrict__ b2, int M,
                      unsigned short* __restrict__ rh, float* __restrict__ oacc,
                      const float* __restrict__ gamma) {
  // LDS union: stage-1 staging (A f32 16KB @0, B bf16 32KB @16K) -> stage-2 h1 128KB @0
  __shared__ char smem[131072];
  float4* Asv = (float4*)smem;               // A: chunk s = kc*128 + row, kc in 0..7 (4 f32)
  short8* Bsv = (short8*)(smem + 16384);     // B: chunk s = kc*512 + n,  kc in 0..3 (8 bf16)
  short8* H1v = (short8*)smem;               // h1: chunk s = k2c*128 + row, k2c in 0..63
  unsigned short* H1s = (unsigned short*)smem;

  const int tid = threadIdx.x;
  const int lane = tid & 63;
  const int wave = tid >> 6;
  const int wr = wave & 1;       // row half (64 rows)
  const int wp = wave >> 1;      // stage-1: 128-col panel; stage-2: 64-col quarter
  const int m0 = blockIdx.x * 128;
  const int lrow = lane & 15;
  const int kgrp = lane >> 4;

  // stage-1 staging addresses (K-major chunk layout; LDS dest = wave base + lane*16)
  const float* Aga[2];
  char* Ald[2];
#pragma unroll
  for (int c = 0; c < 2; ++c) {
    int s = c * 512 + tid;
    int kc = s >> 7, r = s & 127;
    int gr = m0 + r;
    if (gr >= M) gr = M - 1;     // clamp (dup load; stores are guarded)
    Aga[c] = X + (size_t)gr * IN_C + kc * 4;
    Ald[c] = smem + s * 16;
  }
  const bf16* Bga[4];
  char* Bld[4];
#pragma unroll
  for (int c = 0; c < 4; ++c) {
    int s = c * 512 + tid;
    int kc = s >> 9, n = s & 511;
    Bga[c] = W1T + (size_t)n * IN_C + kc * 8;
    Bld[c] = smem + 16384 + s * 16;
  }

  floatx4 zero = {0.f, 0.f, 0.f, 0.f};
  floatx4 acc1[4][8];
#pragma unroll
  for (int i = 0; i < 4; ++i)
#pragma unroll
    for (int j = 0; j < 8; ++j) acc1[i][j] = zero;

  for (int k0 = 0; k0 < IN_C; k0 += 32) {
#pragma unroll
    for (int c = 0; c < 2; ++c) async_copy16(Aga[c] + k0, Ald[c]);
#pragma unroll
    for (int c = 0; c < 4; ++c) async_copy16(Bga[c] + k0, Bld[c]);
    __syncthreads();  // drains vmcnt before barrier
    short8 a[4];
#pragma unroll
    for (int i = 0; i < 4; ++i) {
      int row = wr * 64 + i * 16 + lrow;
      float4 lo = Asv[(2 * kgrp) * 128 + row];
      float4 hi = Asv[(2 * kgrp + 1) * 128 + row];
      a[i] = pack8(lo, hi);
    }
#pragma unroll
    for (int j = 0; j < 8; ++j) {
      short8 b = Bsv[kgrp * 512 + (wp * 128 + j * 16 + lrow)];
#pragma unroll
      for (int i = 0; i < 4; ++i)
        acc1[i][j] = __builtin_amdgcn_mfma_f32_16x16x32_bf16(a[i], b, acc1[i][j], 0, 0, 0);
    }
    __syncthreads();
  }

  // bias + relu -> h1 LDS (bf16, K-major chunk layout)
  const int crow = (lane >> 4) * 4;
  const int ccol = lane & 15;
#pragma unroll
  for (int j = 0; j < 8; ++j) {
    int col = wp * 128 + j * 16 + ccol;
    float bj = b1[col];
    int cvec = col >> 3, sub = col & 7;
#pragma unroll
    for (int i = 0; i < 4; ++i)
#pragma unroll
      for (int r = 0; r < 4; ++r) {
        int row = wr * 64 + i * 16 + crow + r;
        float v = fmaxf(acc1[i][j][r] + bj, 0.f);
        H1s[(cvec * 128 + row) * 8 + sub] = f2bf(v);
      }
  }
  __syncthreads();

  // stage-2: out[128x256] = h1 @ W2 (+b2); wave (wr, wp) owns 64x64
  floatx4 acc2[4][4];
#pragma unroll
  for (int i = 0; i < 4; ++i)
#pragma unroll
    for (int j = 0; j < 4; ++j) acc2[i][j] = zero;

  for (int step = 0; step < 16; ++step) {
    short8 b2f[4];
#pragma unroll
    for (int j = 0; j < 4; ++j)
      b2f[j] = *(const short8*)(W2T + (size_t)(wp * 64 + j * 16 + lrow) * HID_C +
                                step * 32 + kgrp * 8);
    short8 a2[4];
#pragma unroll
    for (int i = 0; i < 4; ++i)
      a2[i] = H1v[(step * 4 + kgrp) * 128 + (wr * 64 + i * 16 + lrow)];
#pragma unroll
    for (int i = 0; i < 4; ++i)
#pragma unroll
      for (int j = 0; j < 4; ++j)
        acc2[i][j] = __builtin_amdgcn_mfma_f32_16x16x32_bf16(a2[i], b2f[j], acc2[i][j], 0, 0, 0);
  }

  // epilogue: rh = relu(v) bf16 (gather operand; relu(coef*y)==coef*relu(y), coef>=0),
  //           oacc = gamma0 * v (un-relu'd, f32)
  float g0 = gamma[0];
  float bc[4];
#pragma unroll
  for (int j = 0; j < 4; ++j) bc[j] = b2[wp * 64 + j * 16 + ccol];
#pragma unroll
  for (int i = 0; i < 4; ++i) {
#pragma unroll
    for (int r = 0; r < 4; ++r) {
      int gr = m0 + wr * 64 + i * 16 + crow + r;
      if (gr < M) {
#pragma unroll
        for (int j = 0; j < 4; ++j) {
          int gc = wp * 64 + j * 16 + ccol;
          float v = acc2[i][j][r] + bc[j];
          rh[(size_t)gr * OUT_C + gc] = f2bf(fmaxf(v, 0.f));
          oacc[(size_t)gr * OUT_C + gc] = g0 * v;
        }
      }
    }
  }
}

// All K_HOPS hops fused (coef >= 0 => relu(coef*x) = coef*relu(x), telescoping):
//   x_k[e] = (prod_{j<k} coef[c_j]) * relu(h[c_k]),  c_0=e, c_{j+1}=col[c_j]
//   out[e] = gamma0*h[e] + sum_k gamma_k * x_k[e]
// One wave per edge: scalar (SGPR) chain walk, 64 lanes x 4 channels gather/accum.
__global__ void fused_hop_kernel(const unsigned short* __restrict__ rh,
                                 const float* __restrict__ oacc,
                                 float* __restrict__ outp,
                                 const int* __restrict__ colIdx,
                                 const float* __restrict__ coef,
                                 const float* __restrict__ gamma) {
  int gtid = blockIdx.x * 256 + threadIdx.x;
  int e = __builtin_amdgcn_readfirstlane(gtid >> 6);  // wave-uniform edge
  int c4 = (gtid & 63) * 4;

  float4 acc = *(const float4*)(oacc + (size_t)e * 256 + c4);

  int c = e;
  float prod = 1.0f;
#pragma unroll 1
  for (int k = 1; k <= K_HOPS; ++k) {
    prod *= coef[c];                 // P_k = prod_{j<k} coef[c_j]
    if (prod == 0.0f) break;         // exact: all remaining terms are 0
    c = __builtin_amdgcn_readfirstlane(colIdx[c]);
    float w = gamma[k] * prod;
    ushort4 pv = *(const ushort4*)(rh + (size_t)c * 256 + c4);
    acc.x += w * bf2f(pv.x);
    acc.y += w * bf2f(pv.y);
    acc.z += w * bf2f(pv.z);
    acc.w += w * bf2f(pv.w);
  }
  *(float4*)(outp + (size_t)e * 256 + c4) = acc;
}

extern "C" void kernel_launch(void* const* d_in, const int* in_sizes, int n_in,
                              void* d_out, int out_size, void* d_ws, size_t ws_size,
                              hipStream_t stream) {
  const float* x = (const float*)d_in[0];     // [N, 512] f32
  const int* edge = (const int*)d_in[1];      // [2,E] int32: row=edge[0:E), col=edge[E:2E)
  const float* W1 = (const float*)d_in[2];    // [512, 512] f32
  const float* b1 = (const float*)d_in[3];    // [512] f32
  const float* W2 = (const float*)d_in[4];    // [512, 256] f32
  const float* b2 = (const float*)d_in[5];    // [256] f32
  const float* gamma = (const float*)d_in[6]; // [11] f32
  float* out = (float*)d_out;                 // [N, 256] f32

  // workspace layout (bytes), total ~310 MB:
  char* ws = (char*)d_ws;
  unsigned short* rh = (unsigned short*)ws;                // N*256*2 = 102,400,000
  float* oacc = (float*)(ws + 102400000);                  // N*256*4 = 204,800,000
  bf16* W1T = (bf16*)(ws + 307200000);                     // 512*512*2 = 524,288
  bf16* W2T = (bf16*)(ws + 307724288);                     // 256*512*2 = 262,144
  float* deg = (float*)(ws + 307986432);                   // N*4 = 800,000
  float* coef = (float*)(ws + 308786432);                  // E*4 = 800,000

  const int* rowIdx = edge;
  const int* colIdx = edge + N_EDGES;

  hipMemsetAsync(deg, 0, N_NODES * sizeof(float), stream);

  transpose_cast_kernel<<<dim3(IN_C * HID_C / 256), 256, 0, stream>>>(W1, W1T, IN_C, HID_C);
  transpose_cast_kernel<<<dim3(HID_C * OUT_C / 256), 256, 0, stream>>>(W2, W2T, HID_C, OUT_C);

  deg_kernel<<<dim3((N_EDGES + 255) / 256), 256, 0, stream>>>(rowIdx, deg, N_EDGES);
  coef_kernel<<<dim3((N_EDGES + 255) / 256), 256, 0, stream>>>(rowIdx, colIdx, deg, coef, N_EDGES);

  // rh = relu(mlp(x)) bf16 ; oacc = gamma0*mlp(x) f32 — one fused kernel, x read once
  fused_mlp_kernel<<<dim3((N_NODES + 127) / 128), 512, 0, stream>>>(
      x, W1T, b1, W2T, b2, N_NODES, rh, oacc, gamma);

  // all 10 hops in one pass
  fused_hop_kernel<<<dim3(N_EDGES * 64 / 256), 256, 0, stream>>>(
      rh, oacc, out, colIdx, coef, gamma);
}

// Round 3
// 993.505 us; speedup vs baseline: 1.9531x; 1.0584x over previous
//
#include <hip/hip_runtime.h>
#include <hip/hip_bf16.h>

#define N_NODES 200000
#define N_EDGES 200000
#define IN_C 512
#define HID_C 512
#define OUT_C 256
#define K_HOPS 10

typedef __hip_bfloat16 bf16;
typedef __attribute__((ext_vector_type(8))) short short8;
typedef __attribute__((ext_vector_type(4))) float floatx4;

__device__ __forceinline__ float bf2f(unsigned short u) {
  unsigned int x = ((unsigned int)u) << 16;
  return __builtin_bit_cast(float, x);
}
__device__ __forceinline__ unsigned short f2bf(float f) {
  return __builtin_bit_cast(unsigned short, __float2bfloat16(f));
}

// ---- W [K,N] f32 row-major -> WT [N,K] bf16 row-major ----
__global__ void transpose_cast_kernel(const float* __restrict__ W, bf16* __restrict__ WT,
                                      int Kd, int Nd) {
  int idx = blockIdx.x * 256 + threadIdx.x;
  if (idx < Kd * Nd) {
    int k = idx / Nd, n = idx - k * Nd;
    WT[(size_t)n * Kd + k] = __float2bfloat16(W[idx]);
  }
}

__global__ void deg_kernel(const int* __restrict__ rowIdx, float* __restrict__ deg, int E) {
  int e = blockIdx.x * 256 + threadIdx.x;
  if (e < E) atomicAdd(&deg[rowIdx[e]], 1.0f);
}

__global__ void coef_kernel(const int* __restrict__ rowIdx, const int* __restrict__ colIdx,
                            const float* __restrict__ deg, float* __restrict__ coef, int E) {
  int e = blockIdx.x * 256 + threadIdx.x;
  if (e < E) {
    float dr = deg[rowIdx[e]];
    float dc = deg[colIdx[e]];
    float a = dr > 0.f ? rsqrtf(dr) : 0.f;
    float b = dc > 0.f ? rsqrtf(dc) : 0.f;
    coef[e] = a * b;
  }
}

// Fused MLP v2: 64-row tile, 8 waves, 2 blocks/CU.
//   rh  = relu(relu(X@W1+b1)@W2+b2)  bf16   (gather operand for hops)
//   oacc= gamma0*(relu(X@W1+b1)@W2+b2) f32
// Stage-1: wave w owns 64x64 col-panel of h1 (acc1[4][4]); X reg-staged f32->bf16 into
//   a double-buffered LDS tile (stride-66 chunk layout -> all LDS ops conflict-free);
//   W1T fragments read from global (L2-hot), next-iter frags prefetched into regs
//   BEFORE the barrier. One barrier per K-step.
// Stage-2: h1 (64x512 bf16, LDS) @ W2T (global, L2-hot), no barriers.
// LDS 76,032 B -> 2 blocks/CU; launch_bounds(512,4) -> VGPR<=128, 16 waves/CU.
__global__ __launch_bounds__(512, 4)
void fused_mlp_kernel(const float* __restrict__ X, const bf16* __restrict__ W1T,
                      const float* __restrict__ b1, const bf16* __restrict__ W2T,
                      const float* __restrict__ b2,
                      unsigned short* __restrict__ rh, float* __restrict__ oacc,
                      const float* __restrict__ gamma) {
  // layout: H1 [0, 67584) : 64 kc-chunks x stride 66 x 16B (8 bf16 per chunk-row)
  //         A dbuf [67584, 76032) : 2 x (4 kc-chunks x stride 66 x 16B)
  __shared__ __align__(16) char smem[76032];
  unsigned short* H1 = (unsigned short*)smem;
  char* const Abase = smem + 67584;

  const int tid = threadIdx.x;
  const int lane = tid & 63;
  const int w = tid >> 6;            // wave 0..7
  const int m0 = blockIdx.x * 64;    // 200000 = 3125*64 exact -> no OOB anywhere
  const int lrow = lane & 15;
  const int kgrp = lane >> 4;        // 0..3

  // ---- A staging map: thread -> (row, k-quad) ----
  const int srow = tid >> 3;         // 0..63
  const int q = tid & 7;             // 4-float quad within 32-k step
  const float* Xp = X + (size_t)(m0 + srow) * IN_C + q * 4;
  const int aoff = ((q >> 1) * 66 + srow) * 16 + (q & 1) * 8;  // byte off in A buf

  // ---- stage-1 B fragment pointers (W1T n-major [512,512] bf16) ----
  const bf16* B1p[4];
#pragma unroll
  for (int j = 0; j < 4; ++j)
    B1p[j] = W1T + (size_t)(w * 64 + j * 16 + lrow) * IN_C + kgrp * 8;

  floatx4 zero = {0.f, 0.f, 0.f, 0.f};
  floatx4 acc1[4][4];
#pragma unroll
  for (int i = 0; i < 4; ++i)
#pragma unroll
    for (int j = 0; j < 4; ++j) acc1[i][j] = zero;

  // prologue: stage A(k0=0), prefetch B(k0=0)
  short8 bcur[4];
  {
    float4 v = *(const float4*)Xp;
#pragma unroll
    for (int j = 0; j < 4; ++j) bcur[j] = *(const short8*)(B1p[j]);
    ushort4 p;
    p.x = f2bf(v.x); p.y = f2bf(v.y); p.z = f2bf(v.z); p.w = f2bf(v.w);
    *(ushort4*)(Abase + aoff) = p;
  }
  __syncthreads();

  int cur = 0;
  for (int k0 = 0; k0 < IN_C; k0 += 32) {
    const bool more = (k0 + 32) < IN_C;
    float4 nv;
    short8 bnext[4];
    if (more) {
      nv = *(const float4*)(Xp + k0 + 32);        // issued early, consumed late (T14)
#pragma unroll
      for (int j = 0; j < 4; ++j) bnext[j] = *(const short8*)(B1p[j] + k0 + 32);
    }
    const char* rb = Abase + cur * 4224;
#pragma unroll
    for (int i = 0; i < 4; ++i) {
      short8 a = *(const short8*)(rb + (kgrp * 66 + i * 16 + lrow) * 16);
#pragma unroll
      for (int j = 0; j < 4; ++j)
        acc1[i][j] = __builtin_amdgcn_mfma_f32_16x16x32_bf16(a, bcur[j], acc1[i][j], 0, 0, 0);
    }
    if (more) {
      ushort4 p;
      p.x = f2bf(nv.x); p.y = f2bf(nv.y); p.z = f2bf(nv.z); p.w = f2bf(nv.w);
      *(ushort4*)(Abase + (cur ^ 1) * 4224 + aoff) = p;
#pragma unroll
      for (int j = 0; j < 4; ++j) bcur[j] = bnext[j];
    }
    __syncthreads();
    cur ^= 1;
  }

  // ---- h1 = relu(acc1 + b1) -> LDS (chunk layout, ~2-way conflicts max) ----
  const int crow = (lane >> 4) * 4;
  const int ccol = lane & 15;
#pragma unroll
  for (int j = 0; j < 4; ++j) {
    int col = w * 64 + j * 16 + ccol;
    float bj = b1[col];
    int cbase = (col >> 3) * 66;
    int sub = col & 7;
#pragma unroll
    for (int i = 0; i < 4; ++i)
#pragma unroll
      for (int r = 0; r < 4; ++r) {
        int row = i * 16 + crow + r;
        H1[(cbase + row) * 8 + sub] = f2bf(fmaxf(acc1[i][j][r] + bj, 0.f));
      }
  }
  __syncthreads();

  // ---- stage-2: out[64x256] = h1 @ W2 (+b2); wave w owns 32-col panel ----
  floatx4 acc2[4][2];
#pragma unroll
  for (int i = 0; i < 4; ++i)
#pragma unroll
    for (int j = 0; j < 2; ++j) acc2[i][j] = zero;

  const bf16* B2p[2];
#pragma unroll
  for (int j = 0; j < 2; ++j)
    B2p[j] = W2T + (size_t)(w * 32 + j * 16 + lrow) * HID_C + kgrp * 8;

  for (int step = 0; step < 16; ++step) {
    short8 bb[2];
#pragma unroll
    for (int j = 0; j < 2; ++j) bb[j] = *(const short8*)(B2p[j] + step * 32);
#pragma unroll
    for (int i = 0; i < 4; ++i) {
      short8 a = *(const short8*)(smem + ((step * 4 + kgrp) * 66 + i * 16 + lrow) * 16);
#pragma unroll
      for (int j = 0; j < 2; ++j)
        acc2[i][j] = __builtin_amdgcn_mfma_f32_16x16x32_bf16(a, bb[j], acc2[i][j], 0, 0, 0);
    }
  }

  // ---- epilogue: rh = relu(v) bf16 (relu(coef*y)==coef*relu(y), coef>=0),
  //                oacc = gamma0 * v (un-relu'd, f32). No row guard (exact tiling).
  float g0 = gamma[0];
  float bc[2];
#pragma unroll
  for (int j = 0; j < 2; ++j) bc[j] = b2[w * 32 + j * 16 + ccol];
#pragma unroll
  for (int i = 0; i < 4; ++i)
#pragma unroll
    for (int r = 0; r < 4; ++r) {
      int gr = m0 + i * 16 + crow + r;
#pragma unroll
      for (int j = 0; j < 2; ++j) {
        int gc = w * 32 + j * 16 + ccol;
        float v = acc2[i][j][r] + bc[j];
        rh[(size_t)gr * OUT_C + gc] = f2bf(fmaxf(v, 0.f));
        oacc[(size_t)gr * OUT_C + gc] = g0 * v;
      }
    }
}

// All K_HOPS hops fused (coef >= 0 => relu(coef*x) = coef*relu(x), telescoping):
//   x_k[e] = (prod_{j<k} coef[c_j]) * relu(h[c_k]),  c_0=e, c_{j+1}=col[c_j]
//   out[e] = gamma0*h[e] + sum_k gamma_k * x_k[e]
// One wave per edge: scalar (SGPR) chain walk, 64 lanes x 4 channels gather/accum.
__global__ void fused_hop_kernel(const unsigned short* __restrict__ rh,
                                 const float* __restrict__ oacc,
                                 float* __restrict__ outp,
                                 const int* __restrict__ colIdx,
                                 const float* __restrict__ coef,
                                 const float* __restrict__ gamma) {
  int gtid = blockIdx.x * 256 + threadIdx.x;
  int e = __builtin_amdgcn_readfirstlane(gtid >> 6);  // wave-uniform edge
  int c4 = (gtid & 63) * 4;

  float4 acc = *(const float4*)(oacc + (size_t)e * 256 + c4);

  int c = e;
  float prod = 1.0f;
#pragma unroll 1
  for (int k = 1; k <= K_HOPS; ++k) {
    prod *= coef[c];                 // P_k = prod_{j<k} coef[c_j]
    if (prod == 0.0f) break;         // exact: all remaining terms are 0
    c = __builtin_amdgcn_readfirstlane(colIdx[c]);
    float w = gamma[k] * prod;
    ushort4 pv = *(const ushort4*)(rh + (size_t)c * 256 + c4);
    acc.x += w * bf2f(pv.x);
    acc.y += w * bf2f(pv.y);
    acc.z += w * bf2f(pv.z);
    acc.w += w * bf2f(pv.w);
  }
  *(float4*)(outp + (size_t)e * 256 + c4) = acc;
}

extern "C" void kernel_launch(void* const* d_in, const int* in_sizes, int n_in,
                              void* d_out, int out_size, void* d_ws, size_t ws_size,
                              hipStream_t stream) {
  const float* x = (const float*)d_in[0];     // [N, 512] f32
  const int* edge = (const int*)d_in[1];      // [2,E] int32: row=edge[0:E), col=edge[E:2E)
  const float* W1 = (const float*)d_in[2];    // [512, 512] f32
  const float* b1 = (const float*)d_in[3];    // [512] f32
  const float* W2 = (const float*)d_in[4];    // [512, 256] f32
  const float* b2 = (const float*)d_in[5];    // [256] f32
  const float* gamma = (const float*)d_in[6]; // [11] f32
  float* out = (float*)d_out;                 // [N, 256] f32

  // workspace layout (bytes), total ~310 MB:
  char* ws = (char*)d_ws;
  unsigned short* rh = (unsigned short*)ws;                // N*256*2 = 102,400,000
  float* oacc = (float*)(ws + 102400000);                  // N*256*4 = 204,800,000
  bf16* W1T = (bf16*)(ws + 307200000);                     // 512*512*2 = 524,288
  bf16* W2T = (bf16*)(ws + 307724288);                     // 256*512*2 = 262,144
  float* deg = (float*)(ws + 307986432);                   // N*4 = 800,000
  float* coef = (float*)(ws + 308786432);                  // E*4 = 800,000

  const int* rowIdx = edge;
  const int* colIdx = edge + N_EDGES;

  hipMemsetAsync(deg, 0, N_NODES * sizeof(float), stream);

  transpose_cast_kernel<<<dim3(IN_C * HID_C / 256), 256, 0, stream>>>(W1, W1T, IN_C, HID_C);
  transpose_cast_kernel<<<dim3(HID_C * OUT_C / 256), 256, 0, stream>>>(W2, W2T, HID_C, OUT_C);

  deg_kernel<<<dim3((N_EDGES + 255) / 256), 256, 0, stream>>>(rowIdx, deg, N_EDGES);
  coef_kernel<<<dim3((N_EDGES + 255) / 256), 256, 0, stream>>>(rowIdx, colIdx, deg, coef, N_EDGES);

  // rh = relu(mlp(x)) bf16 ; oacc = gamma0*mlp(x) f32 — one fused kernel, x read once
  fused_mlp_kernel<<<dim3(N_NODES / 64), 512, 0, stream>>>(
      x, W1T, b1, W2T, b2, rh, oacc, gamma);

  // all 10 hops in one pass
  fused_hop_kernel<<<dim3(N_EDGES * 64 / 256), 256, 0, stream>>>(
      rh, oacc, out, colIdx, coef, gamma);
}